// Round 7
// baseline (33.916 us; speedup 1.0000x reference)
//
#include <hip/hip_runtime.h>

#define NEG_INF_F (-10000.0f)
#define EPS_F (1e-8f)

typedef float f4 __attribute__((ext_vector_type(4)));

// ---------------------------------------------------------------------------
// Kernel A fast path: q1/q2 staged in LDS (8 KB/block, loaded once per
// block), 4 rows per wave with the proven depth-2 register pipeline for the
// streamed row data. __launch_bounds__(256,8) forces VGPR <= 64 so 8 waves
// per SIMD are resident (2x the round-5 occupancy) -- the theory under test.
// Per-row arithmetic (load order, FMA order, 6-level butterfly) is identical
// to round 5 => bit-identical results.
// ---------------------------------------------------------------------------
template <int H>
__global__ __launch_bounds__(256, 8) void row_stats_ldsq(
    const float* __restrict__ seq, const int* __restrict__ idxs,
    float* __restrict__ d1, float* __restrict__ d2, float* __restrict__ n2,
    int S, int nrows) {
  constexpr int NF4 = H / 4;   // f4 per row (256 for H=1024)
  constexpr int C = H / 256;   // f4 loads per lane per row (4)
  constexpr int R = 4;         // rows per wave (pipelined)
  __shared__ f4 q1s[NF4];
  __shared__ f4 q2s[NF4];

  int tid = threadIdx.x;
  int lane = tid & 63;
  int wave = blockIdx.x * 4 + (tid >> 6);
  int row0 = wave * R;         // grid sized so row0 < nrows always
  int b = (blockIdx.x * 16) / S;  // 16 rows/block, 16 | S -> one batch/block
  int sep0 = idxs[2 * b];

  const f4* base = reinterpret_cast<const f4*>(seq);
  // Cooperative q staging: 256 threads x 1 f4 each (NF4 == 256 for H=1024).
  q1s[tid] = base[((size_t)b * S + 1) * NF4 + tid];
  q2s[tid] = base[((size_t)b * S + (sep0 - 1)) * NF4 + tid];
  __syncthreads();

  const f4* rp = base + (size_t)row0 * NF4 + lane;
  f4 x[2][C];
  #pragma unroll
  for (int i = 0; i < C; ++i) x[0][i] = __builtin_nontemporal_load(rp + i * 64);

  #pragma unroll
  for (int r = 0; r < R; ++r) {
    if (r + 1 < R) {
      const f4* np = rp + (size_t)(r + 1) * NF4;
      #pragma unroll
      for (int i = 0; i < C; ++i)
        x[(r + 1) & 1][i] = __builtin_nontemporal_load(np + i * 64);
    }
    float s1 = 0.f, s2 = 0.f, sn = 0.f;
    #pragma unroll
    for (int i = 0; i < C; ++i) {
      f4 v = x[r & 1][i];
      f4 a = q1s[i * 64 + lane];
      f4 c = q2s[i * 64 + lane];
      s1 += v[0] * a[0] + v[1] * a[1] + v[2] * a[2] + v[3] * a[3];
      s2 += v[0] * c[0] + v[1] * c[1] + v[2] * c[2] + v[3] * c[3];
      sn += v[0] * v[0] + v[1] * v[1] + v[2] * v[2] + v[3] * v[3];
    }
    #pragma unroll
    for (int off = 32; off >= 1; off >>= 1) {
      s1 += __shfl_xor(s1, off, 64);
      s2 += __shfl_xor(s2, off, 64);
      sn += __shfl_xor(sn, off, 64);
    }
    if (lane == 0) {
      d1[row0 + r] = s1;
      d2[row0 + r] = s2;
      n2[row0 + r] = sn;
    }
  }
}

// Generic fallback (runtime H): one wave per row.
__global__ __launch_bounds__(256) void row_stats_kernel(
    const float* __restrict__ seq, const int* __restrict__ idxs,
    float* __restrict__ d1, float* __restrict__ d2, float* __restrict__ n2,
    int B, int S, int H) {
  int gtid = blockIdx.x * blockDim.x + threadIdx.x;
  int row = gtid >> 6;
  int lane = threadIdx.x & 63;
  int nrows = B * S;
  if (row >= nrows) return;

  int b = row / S;
  int sep0 = idxs[b * 2 + 0];

  const float* rowp = seq + (size_t)row * H;
  const float* q1p = seq + ((size_t)b * S + 1) * H;
  const float* q2p = seq + ((size_t)b * S + (sep0 - 1)) * H;

  float s1 = 0.f, s2 = 0.f, sn = 0.f;
  for (int h = lane * 4; h < H; h += 64 * 4) {
    float4 x = *reinterpret_cast<const float4*>(rowp + h);
    float4 a = *reinterpret_cast<const float4*>(q1p + h);
    float4 c = *reinterpret_cast<const float4*>(q2p + h);
    s1 += x.x * a.x + x.y * a.y + x.z * a.z + x.w * a.w;
    s2 += x.x * c.x + x.y * c.y + x.z * c.z + x.w * c.w;
    sn += x.x * x.x + x.y * x.y + x.z * x.z + x.w * x.w;
  }
  #pragma unroll
  for (int off = 32; off >= 1; off >>= 1) {
    s1 += __shfl_xor(s1, off, 64);
    s2 += __shfl_xor(s2, off, 64);
    sn += __shfl_xor(sn, off, 64);
  }
  if (lane == 0) {
    d1[row] = s1;
    d2[row] = s2;
    n2[row] = sn;
  }
}

// ---------------------------------------------------------------------------
// Kernel B (round-5 proven version): one thread per (b,s), L=32 full unroll,
// rsqrt. 64-thread blocks -> 512 blocks over 256 CUs. First-occurrence
// argmax via strict '>' (matches jnp.argmax).
// ---------------------------------------------------------------------------
template <int L>
__global__ __launch_bounds__(64) void window_max_fast(
    const float* __restrict__ d1, const float* __restrict__ d2,
    const float* __restrict__ n2, const int* __restrict__ idxs,
    float* __restrict__ out, int S, int nrows) {
  int t = blockIdx.x * 64 + threadIdx.x;
  if (t >= nrows) return;
  int b = t / S;
  int s = t - b * S;

  int sep0 = idxs[b * 2 + 0];
  int sep1 = idxs[b * 2 + 1];

  size_t bS = (size_t)b * S;
  float qn2 = n2[bS + 1] + n2[bS + (sep0 - 1)];
  float my_d1 = d1[t];
  float my_n2 = n2[t];

  const float* d2b = d2 + bS;
  const float* n2b = n2 + bS;

  float best = NEG_INF_F;
  int best_l = 0;
  #pragma unroll
  for (int l = 0; l < L; ++l) {
    int j = min(s + l, S - 1);
    float w2 = n2b[j];
    float v2 = d2b[j];
    float prod = (my_n2 + w2) * qn2;
    float sim = (my_d1 + v2) * __frsqrt_rn(fmaxf(prod, EPS_F * EPS_F));
    sim = (s + l < sep1) ? sim : NEG_INF_F;
    if (sim > best) { best = sim; best_l = l; }
  }

  bool valid_i = (s > sep0) && (s < sep1);
  out[t] = valid_i ? best : NEG_INF_F;
  out[nrows + t] = valid_i ? (float)(s + best_l) : -1.0f;
}

extern "C" void kernel_launch(void* const* d_in, const int* in_sizes, int n_in,
                              void* d_out, int out_size, void* d_ws, size_t ws_size,
                              hipStream_t stream) {
  const float* seq = (const float*)d_in[0];
  const int* idxs = (const int*)d_in[1];
  const int* pL = (const int*)d_in[2];

  int B = in_sizes[1] / 2;
  int S = out_size / (2 * B);
  int H = (int)((long long)in_sizes[0] / ((long long)B * S));
  int nrows = B * S;

  float* d1 = (float*)d_ws;
  float* d2 = d1 + nrows;
  float* n2 = d2 + nrows;

  if (H == 1024 && (S % 16) == 0 && (nrows % 16) == 0) {
    // 4 rows per wave (pipelined), 4 waves per block -> 16 rows per block;
    // q1/q2 staged in LDS once per block.
    int gridA = nrows / 16;
    row_stats_ldsq<1024><<<gridA, 256, 0, stream>>>(seq, idxs, d1, d2, n2, S,
                                                    nrows);
  } else {
    int gridA = (nrows + 3) / 4;
    row_stats_kernel<<<gridA, 256, 0, stream>>>(seq, idxs, d1, d2, n2, B, S, H);
  }

  int gridB = (nrows + 63) / 64;
  window_max_fast<32><<<gridB, 64, 0, stream>>>(d1, d2, n2, idxs,
                                                (float*)d_out, S, nrows);
  (void)pL;
}

// Round 8
// 30.988 us; speedup vs baseline: 1.0945x; 1.0945x over previous
//
#include <hip/hip_runtime.h>

#define NEG_INF_F (-10000.0f)
#define EPS_F (1e-8f)

typedef float f4 __attribute__((ext_vector_type(4)));

// ---------------------------------------------------------------------------
// Kernel A (round-5 structure, ONE change: plain loads instead of
// non-temporal). seq is 124 MB < 256 MB Infinity Cache; without the nt hint
// the tensor stays L3-resident across graph replays and reads are served at
// L3 bandwidth instead of HBM. One wave per 4 consecutive rows, depth-2
// register pipeline, q1/q2 hoisted per wave. Arithmetic identical to r5.
// ---------------------------------------------------------------------------
template <int H>
__global__ __launch_bounds__(256) void row_stats_pipe(
    const float* __restrict__ seq, const int* __restrict__ idxs,
    float* __restrict__ d1, float* __restrict__ d2, float* __restrict__ n2,
    int S, int nrows) {
  constexpr int NF4 = H / 4;   // f4 per row
  constexpr int C = H / 256;   // f4 loads per lane per row (4 for H=1024)
  constexpr int R = 4;         // rows per wave (pipelined)
  int wave = blockIdx.x * 4 + (threadIdx.x >> 6);
  int lane = threadIdx.x & 63;
  int row0 = wave * R;
  if (row0 >= nrows) return;

  int b = row0 / S;            // S % 4 == 0 -> all R rows in one batch
  int sep0 = idxs[2 * b];

  const f4* base = reinterpret_cast<const f4*>(seq);
  const f4* q1p = base + ((size_t)b * S + 1) * NF4 + lane;
  const f4* q2p = base + ((size_t)b * S + (sep0 - 1)) * NF4 + lane;
  const f4* rp = base + (size_t)row0 * NF4 + lane;

  f4 q1f[C], q2f[C], x[2][C];
  #pragma unroll
  for (int i = 0; i < C; ++i) q1f[i] = q1p[i * 64];
  #pragma unroll
  for (int i = 0; i < C; ++i) q2f[i] = q2p[i * 64];
  #pragma unroll
  for (int i = 0; i < C; ++i) x[0][i] = rp[i * 64];

  #pragma unroll
  for (int r = 0; r < R; ++r) {
    // Next row's loads issued before this row's reduce (stay in flight
    // through the FMA + shuffle chain; vmcnt wait lands next iteration).
    if (r + 1 < R) {
      const f4* np = rp + (size_t)(r + 1) * NF4;
      #pragma unroll
      for (int i = 0; i < C; ++i) x[(r + 1) & 1][i] = np[i * 64];
    }
    float s1 = 0.f, s2 = 0.f, sn = 0.f;
    #pragma unroll
    for (int i = 0; i < C; ++i) {
      f4 v = x[r & 1][i];
      s1 += v[0] * q1f[i][0] + v[1] * q1f[i][1] + v[2] * q1f[i][2] + v[3] * q1f[i][3];
      s2 += v[0] * q2f[i][0] + v[1] * q2f[i][1] + v[2] * q2f[i][2] + v[3] * q2f[i][3];
      sn += v[0] * v[0] + v[1] * v[1] + v[2] * v[2] + v[3] * v[3];
    }
    #pragma unroll
    for (int off = 32; off >= 1; off >>= 1) {
      s1 += __shfl_xor(s1, off, 64);
      s2 += __shfl_xor(s2, off, 64);
      sn += __shfl_xor(sn, off, 64);
    }
    if (lane == 0) {
      d1[row0 + r] = s1;
      d2[row0 + r] = s2;
      n2[row0 + r] = sn;
    }
  }
}

// Generic fallback (runtime H): one wave per row.
__global__ __launch_bounds__(256) void row_stats_kernel(
    const float* __restrict__ seq, const int* __restrict__ idxs,
    float* __restrict__ d1, float* __restrict__ d2, float* __restrict__ n2,
    int B, int S, int H) {
  int gtid = blockIdx.x * blockDim.x + threadIdx.x;
  int row = gtid >> 6;
  int lane = threadIdx.x & 63;
  int nrows = B * S;
  if (row >= nrows) return;

  int b = row / S;
  int sep0 = idxs[b * 2 + 0];

  const float* rowp = seq + (size_t)row * H;
  const float* q1p = seq + ((size_t)b * S + 1) * H;
  const float* q2p = seq + ((size_t)b * S + (sep0 - 1)) * H;

  float s1 = 0.f, s2 = 0.f, sn = 0.f;
  for (int h = lane * 4; h < H; h += 64 * 4) {
    float4 x = *reinterpret_cast<const float4*>(rowp + h);
    float4 a = *reinterpret_cast<const float4*>(q1p + h);
    float4 c = *reinterpret_cast<const float4*>(q2p + h);
    s1 += x.x * a.x + x.y * a.y + x.z * a.z + x.w * a.w;
    s2 += x.x * c.x + x.y * c.y + x.z * c.z + x.w * c.w;
    sn += x.x * x.x + x.y * x.y + x.z * x.z + x.w * x.w;
  }
  #pragma unroll
  for (int off = 32; off >= 1; off >>= 1) {
    s1 += __shfl_xor(s1, off, 64);
    s2 += __shfl_xor(s2, off, 64);
    sn += __shfl_xor(sn, off, 64);
  }
  if (lane == 0) {
    d1[row] = s1;
    d2[row] = s2;
    n2[row] = sn;
  }
}

// ---------------------------------------------------------------------------
// Kernel B (round-5 proven version): one thread per (b,s), L=32 full unroll,
// rsqrt. First-occurrence argmax via strict '>' (matches jnp.argmax).
// ---------------------------------------------------------------------------
template <int L>
__global__ __launch_bounds__(64) void window_max_fast(
    const float* __restrict__ d1, const float* __restrict__ d2,
    const float* __restrict__ n2, const int* __restrict__ idxs,
    float* __restrict__ out, int S, int nrows) {
  int t = blockIdx.x * 64 + threadIdx.x;
  if (t >= nrows) return;
  int b = t / S;
  int s = t - b * S;

  int sep0 = idxs[b * 2 + 0];
  int sep1 = idxs[b * 2 + 1];

  size_t bS = (size_t)b * S;
  float qn2 = n2[bS + 1] + n2[bS + (sep0 - 1)];
  float my_d1 = d1[t];
  float my_n2 = n2[t];

  const float* d2b = d2 + bS;
  const float* n2b = n2 + bS;

  float best = NEG_INF_F;
  int best_l = 0;
  #pragma unroll
  for (int l = 0; l < L; ++l) {
    int j = min(s + l, S - 1);
    float w2 = n2b[j];
    float v2 = d2b[j];
    float prod = (my_n2 + w2) * qn2;
    float sim = (my_d1 + v2) * __frsqrt_rn(fmaxf(prod, EPS_F * EPS_F));
    sim = (s + l < sep1) ? sim : NEG_INF_F;
    if (sim > best) { best = sim; best_l = l; }
  }

  bool valid_i = (s > sep0) && (s < sep1);
  out[t] = valid_i ? best : NEG_INF_F;
  out[nrows + t] = valid_i ? (float)(s + best_l) : -1.0f;
}

extern "C" void kernel_launch(void* const* d_in, const int* in_sizes, int n_in,
                              void* d_out, int out_size, void* d_ws, size_t ws_size,
                              hipStream_t stream) {
  const float* seq = (const float*)d_in[0];
  const int* idxs = (const int*)d_in[1];
  const int* pL = (const int*)d_in[2];

  int B = in_sizes[1] / 2;
  int S = out_size / (2 * B);
  int H = (int)((long long)in_sizes[0] / ((long long)B * S));
  int nrows = B * S;

  float* d1 = (float*)d_ws;
  float* d2 = d1 + nrows;
  float* n2 = d2 + nrows;

  if (H == 1024 && (S % 4) == 0 && (nrows % 16) == 0) {
    // 4 rows per wave (pipelined), 4 waves per block -> 16 rows per block.
    int gridA = nrows / 16;
    row_stats_pipe<1024><<<gridA, 256, 0, stream>>>(seq, idxs, d1, d2, n2, S,
                                                    nrows);
  } else {
    int gridA = (nrows + 3) / 4;
    row_stats_kernel<<<gridA, 256, 0, stream>>>(seq, idxs, d1, d2, n2, B, S, H);
  }

  int gridB = (nrows + 63) / 64;
  window_max_fast<32><<<gridB, 64, 0, stream>>>(d1, d2, n2, idxs,
                                                (float*)d_out, S, nrows);
  (void)pL;
}